// Round 2
// baseline (1462.468 us; speedup 1.0000x reference)
//
#include <hip/hip_runtime.h>

#define BATCH 16384
#define NUM   512
#define CONS  512
#define MAXI  128          // max i-steps (pairs of literals) per constraint
#define ROWS_PER_BLOCK 64

typedef _Float16 h2 __attribute__((ext_vector_type(2)));

static __device__ __forceinline__ h2 u2h(unsigned int u) {
  return __builtin_bit_cast(h2, u);
}
static __device__ __forceinline__ unsigned int h2u(h2 h) {
  return __builtin_bit_cast(unsigned int, h);
}
static __device__ __forceinline__ h2 hmax2(h2 a, h2 b) {
  return __builtin_elementwise_max(a, b);
}
static __device__ __forceinline__ h2 hmin2(h2 a, h2 b) {
  return __builtin_elementwise_min(a, b);
}
static __device__ __forceinline__ h2 hfma2(h2 a, h2 b, h2 c) {
  return __builtin_elementwise_fma(a, b, c);
}

// ---------------- prep: build sparse literal lists ----------------
// entry i-step = uint4 {off_g0, w_g0, off_g1, w_g1}; w = A2half | B2half<<16
// val = A*p + B.  neg lit: A=+1(0x3C00),B=0 ; pos lit: A=-1(0xBC00),B=+1(0x3C00)
// dummy: A=0,B=-1(0xBC00) -> val = -1 <= 0 (harmless: body floored at 0)
__global__ __launch_bounds__(64) void prep_kernel(
    const float* __restrict__ pos, const float* __restrict__ neg,
    const int* __restrict__ head_atom, const int* __restrict__ head_sign,
    unsigned int* __restrict__ meta, uint4* __restrict__ ents) {
  int c = blockIdx.x;
  int lane = threadIdx.x;
  __shared__ int cnt;
  __shared__ uint2 buf[2 * MAXI];
  if (lane == 0) cnt = 0;
  for (int j = lane; j < 2 * MAXI; j += 64) buf[j] = make_uint2(0u, 0xBC000000u);
  __syncthreads();
  for (int k = 0; k < NUM / 64; ++k) {
    int a = k * 64 + lane;
    float pv = pos[c * NUM + a];
    float nv = neg[c * NUM + a];
    if (pv != 0.0f) {
      int j = atomicAdd(&cnt, 1);
      if (j < 2 * MAXI) buf[j] = make_uint2((unsigned)(a * 128), 0x3C00BC00u);
    }
    if (nv != 0.0f) {
      int j = atomicAdd(&cnt, 1);
      if (j < 2 * MAXI) buf[j] = make_uint2((unsigned)(a * 128), 0x00003C00u);
    }
  }
  __syncthreads();
  int n = cnt; if (n > 2 * MAXI) n = 2 * MAXI;
  // i-steps: ceil(n/2), rounded up to multiple of 8 (inner loop unrolled by 8)
  unsigned int NU = ((unsigned)(((n + 1) >> 1) + 7)) & ~7u;
  for (int i = lane; i < MAXI; i += 64) {
    uint2 a0 = buf[2 * i], a1 = buf[2 * i + 1];
    ents[c * MAXI + i] = make_uint4(a0.x, a0.y, a1.x, a1.y);
  }
  if (lane == 0) {
    unsigned int hoff = (unsigned)head_atom[c] * 128u;
    unsigned int sgn = head_sign[c] ? 1u : 0u;
    meta[c] = hoff | (sgn << 16) | (NU << 17);
  }
}

// ---------------- main: 64 rows per block, p in LDS fp16 [atom][row] ----------------
__global__ __launch_bounds__(64) void solve_kernel(
    const float* __restrict__ preds,
    const unsigned int* __restrict__ meta,
    const uint4* __restrict__ ents,
    float* __restrict__ out) {
  __shared__ unsigned short P[NUM * ROWS_PER_BLOCK];  // 64 KB exactly
  const int lane = threadIdx.x;
  const long long row = (long long)blockIdx.x * ROWS_PER_BLOCK + lane;

  // load: lane <-> row; per-lane sequential float4 along its row (line reuse via L1/L2)
  const float* src = preds + row * NUM;
  #pragma unroll 4
  for (int a = 0; a < NUM; a += 4) {
    float4 v = *(const float4*)(src + a);
    P[(a + 0) * 64 + lane] = __builtin_bit_cast(unsigned short, (_Float16)v.x);
    P[(a + 1) * 64 + lane] = __builtin_bit_cast(unsigned short, (_Float16)v.y);
    P[(a + 2) * 64 + lane] = __builtin_bit_cast(unsigned short, (_Float16)v.z);
    P[(a + 3) * 64 + lane] = __builtin_bit_cast(unsigned short, (_Float16)v.w);
  }
  __syncthreads();

  const int pr = lane & 31;            // row-pair index
  const unsigned int hi = (unsigned)lane >> 5;  // literal group
  char* Pb = (char*)P;
  const unsigned int pb = (unsigned)pr * 4u;    // byte offset of pair within atom row
  const h2 zero2 = (h2)0.0f;
  const h2 one2  = {(_Float16)1.0f, (_Float16)1.0f};

  #pragma unroll 1
  for (int c = 0; c < CONS; ++c) {
    const unsigned int m = meta[c];           // uniform -> s_load
    const unsigned int NU = m >> 17;
    const uint4* __restrict__ E = ents + c * MAXI;
    h2 acc0 = zero2, acc1 = zero2;

#define LIT_STEP(EV, ACC)                                                     \
    {                                                                         \
      unsigned int off = hi ? (EV).z : (EV).x;                                \
      unsigned int w   = hi ? (EV).w : (EV).y;                                \
      unsigned int pv = *(const unsigned int*)(Pb + (off + pb));              \
      h2 A2 = u2h(__builtin_amdgcn_perm(w, w, 0x01000100u));                  \
      h2 B2 = u2h(__builtin_amdgcn_perm(w, w, 0x03020302u));                  \
      ACC = hmax2(ACC, hfma2(A2, u2h(pv), B2));                               \
    }

    for (unsigned int i = 0; i < NU; i += 8) {
      uint4 e0 = E[i + 0], e1 = E[i + 1], e2 = E[i + 2], e3 = E[i + 3];
      uint4 e4 = E[i + 4], e5 = E[i + 5], e6 = E[i + 6], e7 = E[i + 7];
      LIT_STEP(e0, acc0) LIT_STEP(e1, acc1) LIT_STEP(e2, acc0) LIT_STEP(e3, acc1)
      LIT_STEP(e4, acc0) LIT_STEP(e5, acc1) LIT_STEP(e6, acc0) LIT_STEP(e7, acc1)
    }
#undef LIT_STEP

    h2 acc = hmax2(acc0, acc1);
    unsigned int other = (unsigned int)__shfl_xor((int)h2u(acc), 32, 64);
    h2 body = hmax2(acc, u2h(other));     // >= 0 (acc init 0)
    h2 cand = one2 - body;
    unsigned int hoff = m & 0xFFFFu;
    unsigned int pu = *(const unsigned int*)(Pb + (hoff + pb));
    h2 prevv = u2h(pu);
    // sign: max(prev, cand); else: min(prev, 1-cand) == min(prev, body)
    h2 upd = (m & 0x10000u) ? hmax2(prevv, cand) : hmin2(prevv, body);
    if (lane < 32) *(unsigned int*)(Pb + (hoff + pb)) = h2u(upd);
    __builtin_amdgcn_wave_barrier();   // order update before next constraint's reads
  }

  __syncthreads();
  float* dst = out + row * NUM;
  #pragma unroll 4
  for (int a = 0; a < NUM; a += 4) {
    float4 v;
    v.x = (float)__builtin_bit_cast(_Float16, P[(a + 0) * 64 + lane]);
    v.y = (float)__builtin_bit_cast(_Float16, P[(a + 1) * 64 + lane]);
    v.z = (float)__builtin_bit_cast(_Float16, P[(a + 2) * 64 + lane]);
    v.w = (float)__builtin_bit_cast(_Float16, P[(a + 3) * 64 + lane]);
    *(float4*)(dst + a) = v;
  }
}

extern "C" void kernel_launch(void* const* d_in, const int* in_sizes, int n_in,
                              void* d_out, int out_size, void* d_ws, size_t ws_size,
                              hipStream_t stream) {
  (void)in_sizes; (void)n_in; (void)out_size; (void)ws_size;
  const float* preds     = (const float*)d_in[0];
  const float* pos       = (const float*)d_in[1];
  const float* neg       = (const float*)d_in[2];
  const int*   head_atom = (const int*)d_in[3];
  const int*   head_sign = (const int*)d_in[4];

  unsigned int* meta = (unsigned int*)d_ws;                    // 2 KB
  uint4* ents = (uint4*)((char*)d_ws + 4096);                  // 1 MB

  prep_kernel<<<CONS, 64, 0, stream>>>(pos, neg, head_atom, head_sign, meta, ents);
  solve_kernel<<<BATCH / ROWS_PER_BLOCK, 64, 0, stream>>>(
      preds, meta, ents, (float*)d_out);
}

// Round 3
// 545.237 us; speedup vs baseline: 2.6823x; 2.6823x over previous
//
#include <hip/hip_runtime.h>

#define BATCH 16384
#define NUM   512
#define CONS  512
#define RPW   16                    // rows per wave/block
#define ASTR  36                    // LDS byte stride per atom (16 rows*2B + 4B pad; 9 words, coprime 32 banks)
#define ZOFF  (NUM*ASTR)            // zeros scratch (neg-phase dummy)  = 18432
#define OOFF  (NUM*ASTR + 32)      // ones scratch (pos-phase dummy)   = 18464
#define LDSB  (NUM*ASTR + 64)      // 18496 B
#define MAXS  32                    // max total steps per (c,g)

typedef _Float16 h2 __attribute__((ext_vector_type(2)));

static __device__ __forceinline__ h2 u2h(unsigned int u) { return __builtin_bit_cast(h2, u); }
static __device__ __forceinline__ unsigned int h2u(h2 h) { return __builtin_bit_cast(unsigned int, h); }
static __device__ __forceinline__ h2 hmax2(h2 a, h2 b) { return __builtin_elementwise_max(a, b); }
static __device__ __forceinline__ h2 hmin2(h2 a, h2 b) { return __builtin_elementwise_min(a, b); }

// ---------------- prep: per-constraint sign-split literal offset lists ----------------
// ents[(c*8+g)*MAXS + j] = byte offset (atom*ASTR) of literal slot s=j*8+g.
// Neg literals (val = p) first, padded with ZOFF to Sn steps (mult of 4);
// pos literals (val = 1-p -> min over p) next, padded with OOFF to Sp steps.
__global__ __launch_bounds__(64) void prep_kernel(
    const float* __restrict__ pos, const float* __restrict__ neg,
    const int* __restrict__ head_atom, const int* __restrict__ head_sign,
    unsigned int* __restrict__ meta, unsigned int* __restrict__ ents) {
  int c = blockIdx.x, lane = threadIdx.x;
  __shared__ int nn, np;
  __shared__ unsigned short nb[256], pb[256];
  if (lane == 0) { nn = 0; np = 0; }
  __syncthreads();
  for (int k = 0; k < NUM / 64; ++k) {
    int a = k * 64 + lane;
    if (neg[c * NUM + a] != 0.0f) { int j = atomicAdd(&nn, 1); if (j < 256) nb[j] = (unsigned short)(a * ASTR); }
    if (pos[c * NUM + a] != 0.0f) { int j = atomicAdd(&np, 1); if (j < 256) pb[j] = (unsigned short)(a * ASTR); }
  }
  __syncthreads();
  unsigned n = (unsigned)(nn < 256 ? nn : 256);
  unsigned p = (unsigned)(np < 256 ? np : 256);
  unsigned Sn = (((n + 7u) >> 3) + 3u) & ~3u;   // steps, mult of 4 (uint4 chunks)
  unsigned Sp = (((p + 7u) >> 3) + 3u) & ~3u;
  if (Sn > 16u) Sn = 16u;
  if (Sp > 16u) Sp = 16u;
  unsigned base = (unsigned)c * 8u;
  for (unsigned s = lane; s < 8u * Sn; s += 64u) {
    unsigned v = (s < n) ? (unsigned)nb[s] : (unsigned)ZOFF;
    ents[(base + (s & 7u)) * MAXS + (s >> 3)] = v;
  }
  for (unsigned s = lane; s < 8u * Sp; s += 64u) {
    unsigned v = (s < p) ? (unsigned)pb[s] : (unsigned)OOFF;
    ents[(base + (s & 7u)) * MAXS + Sn + (s >> 3)] = v;
  }
  if (lane == 0) {
    unsigned hoff = (unsigned)head_atom[c] * ASTR;   // < 18396, fits 15 bits
    meta[c] = hoff | ((head_sign[c] ? 1u : 0u) << 15) | (Sn << 16) | (Sp << 22);
  }
}

// ---------------- solve: 16 rows per wave, p in LDS fp16 [atom][row] ----------------
// lane = g*8 + pr : g = literal group (8), pr = row-pair (8; half2 = 2 rows)
__global__ __launch_bounds__(64) void solve_kernel(
    const float* __restrict__ preds,
    const unsigned int* __restrict__ meta,
    const unsigned int* __restrict__ ents,
    float* __restrict__ out) {
  __shared__ char Pb[LDSB];
  const int lane = threadIdx.x;
  const int pr = lane & 7;
  const int g = lane >> 3;
  const unsigned pr4 = (unsigned)pr * 4u;
  const long long row0 = (long long)blockIdx.x * RPW;

  if (lane < 8)       *(unsigned*)(Pb + ZOFF + lane * 4) = 0u;
  else if (lane < 16) *(unsigned*)(Pb + OOFF + (lane - 8) * 4) = 0x3C003C00u;

  // stage preds -> LDS fp16, [atom][row]
  for (int rr = 0; rr < RPW; ++rr) {
    const float* src = preds + (row0 + rr) * NUM;
    #pragma unroll
    for (int k = 0; k < NUM / 64; ++k) {
      int a = k * 64 + lane;
      *(_Float16*)(Pb + a * ASTR + rr * 2) = (_Float16)src[a];
    }
  }
  __syncthreads();

  const h2 one2 = {(_Float16)1.0f, (_Float16)1.0f};

  #pragma unroll 1
  for (int c = 0; c < CONS; ++c) {
    const unsigned m = meta[c];
    const unsigned Sn = (m >> 16) & 0x3Fu, Sp = (m >> 22) & 0x3Fu;
    const unsigned* __restrict__ lst = ents + ((unsigned)c * 8u + (unsigned)g) * MAXS;
    h2 accN = (h2)0.0f;   // floor-at-0 built in
    h2 accP = one2;

    #pragma unroll 1
    for (unsigned j = 0; j < Sn; j += 4) {
      uint4 w = *(const uint4*)(lst + j);
      accN = hmax2(accN, *(const h2*)(Pb + (w.x + pr4)));
      accN = hmax2(accN, *(const h2*)(Pb + (w.y + pr4)));
      accN = hmax2(accN, *(const h2*)(Pb + (w.z + pr4)));
      accN = hmax2(accN, *(const h2*)(Pb + (w.w + pr4)));
    }
    const unsigned* __restrict__ lp = lst + Sn;
    #pragma unroll 1
    for (unsigned j = 0; j < Sp; j += 4) {
      uint4 w = *(const uint4*)(lp + j);
      accP = hmin2(accP, *(const h2*)(Pb + (w.x + pr4)));
      accP = hmin2(accP, *(const h2*)(Pb + (w.y + pr4)));
      accP = hmin2(accP, *(const h2*)(Pb + (w.z + pr4)));
      accP = hmin2(accP, *(const h2*)(Pb + (w.w + pr4)));
    }

    const unsigned hoff = m & 0x7FFFu;
    h2 prev = *(const h2*)(Pb + hoff + pr4);        // independent of combine chain

    h2 bp = hmax2(accN, one2 - accP);
    unsigned x = h2u(bp);
    x = h2u(hmax2(u2h(x), u2h((unsigned)__shfl_xor((int)x, 8))));
    x = h2u(hmax2(u2h(x), u2h((unsigned)__shfl_xor((int)x, 16))));
    x = h2u(hmax2(u2h(x), u2h((unsigned)__shfl_xor((int)x, 32))));
    h2 body = u2h(x);                                // >= 0

    h2 upd = (m & 0x8000u) ? hmax2(prev, one2 - body) : hmin2(prev, body);
    if (lane < 8) *(h2*)(Pb + hoff + pr4) = upd;
    __builtin_amdgcn_wave_barrier();   // order head write before next constraint's reads
  }

  __syncthreads();
  for (int rr = 0; rr < RPW; ++rr) {
    float* dst = out + (row0 + rr) * NUM;
    #pragma unroll
    for (int k = 0; k < NUM / 64; ++k) {
      int a = k * 64 + lane;
      dst[a] = (float)*(const _Float16*)(Pb + a * ASTR + rr * 2);
    }
  }
}

extern "C" void kernel_launch(void* const* d_in, const int* in_sizes, int n_in,
                              void* d_out, int out_size, void* d_ws, size_t ws_size,
                              hipStream_t stream) {
  (void)in_sizes; (void)n_in; (void)out_size; (void)ws_size;
  const float* preds     = (const float*)d_in[0];
  const float* pos       = (const float*)d_in[1];
  const float* neg       = (const float*)d_in[2];
  const int*   head_atom = (const int*)d_in[3];
  const int*   head_sign = (const int*)d_in[4];

  unsigned int* meta = (unsigned int*)d_ws;                    // 2 KB
  unsigned int* ents = (unsigned int*)((char*)d_ws + 4096);    // 512 KB

  prep_kernel<<<CONS, 64, 0, stream>>>(pos, neg, head_atom, head_sign, meta, ents);
  solve_kernel<<<BATCH / RPW, 64, 0, stream>>>(preds, meta, ents, (float*)d_out);
}

// Round 4
// 410.842 us; speedup vs baseline: 3.5597x; 1.3271x over previous
//
#include <hip/hip_runtime.h>

#define BATCH 16384
#define NUM   512
#define CONS  512
#define RPW   16                  // rows per wave/block
#define ASTR  36                  // LDS bytes per atom (16 rows*2B + 4B pad; 9 words, odd)
#define ZOFF  (NUM*ASTR)          // zeros scratch (neg dummy)  = 18432
#define OOFF  (NUM*ASTR + 32)     // ones scratch (pos dummy)   = 18464
#define LDSB  (NUM*ASTR + 64)
#define NMETA (CONS + 4)          // prefetch reads up to meta[515]
#define EPC   20                  // entry words per (c,g): 10 neg + 10 pos

typedef _Float16 h2 __attribute__((ext_vector_type(2)));
static __device__ __forceinline__ h2 u2h(unsigned u){return __builtin_bit_cast(h2,u);}
static __device__ __forceinline__ unsigned h2u(h2 h){return __builtin_bit_cast(unsigned,h);}
static __device__ __forceinline__ h2 hmax2(h2 a,h2 b){return __builtin_elementwise_max(a,b);}
static __device__ __forceinline__ h2 hmin2(h2 a,h2 b){return __builtin_elementwise_min(a,b);}

// prep: sign-split literal lists + hazard (h_{c-1} in lits(c)) dummied & flagged.
// meta bits: hoff[14:0] | sign<<15 | patchN<<16 | patchP<<17 | prevpatch<<18 | Sn<<19 | Sp<<23
__global__ __launch_bounds__(64) void prep_kernel(
    const float* __restrict__ pos, const float* __restrict__ neg,
    const int* __restrict__ head_atom, const int* __restrict__ head_sign,
    unsigned* __restrict__ meta, unsigned* __restrict__ ents) {
  int c = blockIdx.x, lane = threadIdx.x;
  if (c >= CONS) { if (!lane) meta[c] = ZOFF; return; }   // Sn=Sp=0, flags 0
  __shared__ int nn, np, fl;
  __shared__ unsigned short nb[96], pb[96];
  if (!lane) { nn = 0; np = 0; fl = 0; }
  __syncthreads();
  for (int k = 0; k < NUM/64; ++k) {
    int a = k*64 + lane;
    if (neg[c*NUM+a] != 0.f) { int j = atomicAdd(&nn,1); if (j < 96) nb[j] = (unsigned short)a; }
    if (pos[c*NUM+a] != 0.f) { int j = atomicAdd(&np,1); if (j < 96) pb[j] = (unsigned short)a; }
  }
  __syncthreads();
  int hp = c ? head_atom[c-1] : -1;
  int n = nn > 80 ? 80 : nn, p = np > 80 ? 80 : np;
  unsigned Sn = (unsigned)((n+7) >> 3), Sp = (unsigned)((p+7) >> 3);
  for (int s = lane; s < 80; s += 64) {
    unsigned g = (unsigned)s & 7u, j = (unsigned)s >> 3;
    unsigned off = ZOFF;
    if (s < n) { int a = nb[s]; if (a == hp) atomicOr(&fl, 1); else off = (unsigned)a*ASTR; }
    ents[((unsigned)c*8u + g)*EPC + j] = off;
    unsigned offp = OOFF;
    if (s < p) { int a = pb[s]; if (a == hp) atomicOr(&fl, 2); else offp = (unsigned)a*ASTR; }
    ents[((unsigned)c*8u + g)*EPC + 10u + j] = offp;
  }
  __syncthreads();
  if (!lane) {
    unsigned ha = (unsigned)head_atom[c];
    unsigned m = ha*ASTR;
    if (head_sign[c]) m |= 1u << 15;
    int f = fl;
    if (f & 1) m |= 1u << 16;
    if (f & 2) m |= 1u << 17;
    if ((int)ha == hp) m |= 1u << 18;
    m |= (Sn << 19) | (Sp << 23);
    meta[c] = m;
  }
}

// solve: pipelined — iter i: [B] prefetch+reduce literals of c=i+1 (pre-hazard-patched),
// then [A] finalize c=i with upd_{i-1} patch and write head. Serial chain = a few VALU ops.
__global__ __launch_bounds__(64) void solve_kernel(
    const float* __restrict__ preds,
    const unsigned* __restrict__ meta,
    const unsigned* __restrict__ ents,
    float* __restrict__ out) {
  __shared__ char Pb[LDSB];
  const int lane = threadIdx.x;
  const int pr = lane & 7, g = lane >> 3;
  const unsigned pr4 = (unsigned)pr*4u;
  const long long row0 = (long long)blockIdx.x * RPW;

  if (lane < 8)       *(unsigned*)(Pb + ZOFF + lane*4) = 0u;
  else if (lane < 16) *(unsigned*)(Pb + OOFF + (lane-8)*4) = 0x3C003C00u;

  for (int rr = 0; rr < RPW; ++rr) {
    const float* src = preds + (row0+rr)*NUM;
    #pragma unroll
    for (int k = 0; k < NUM/64; ++k) {
      int a = k*64 + lane;
      *(_Float16*)(Pb + a*ASTR + rr*2) = (_Float16)src[a];
    }
  }
  __syncthreads();

  const h2 one2 = {(_Float16)1.f, (_Float16)1.f};
  const h2 zero2 = (h2)0.0f;

  auto runB = [&](unsigned mv, const uint4& A0, const uint4& A1, const uint4& A2,
                  const uint4& A3, const uint4& A4, h2& braw, h2& prevraw) {
    unsigned sc = (unsigned)__builtin_amdgcn_readfirstlane((int)mv);
    unsigned Sn = (sc >> 19) & 0xFu, Sp = (sc >> 23) & 0xFu, ho = sc & 0x7FFFu;
    h2 aN = zero2, aP = one2;
#define RN(w) aN = hmax2(aN, *(const h2*)(Pb + ((w) + pr4)))
#define RP(w) aP = hmin2(aP, *(const h2*)(Pb + ((w) + pr4)))
    if (Sn > 0u) { RN(A0.x); RN(A0.y); }
    if (Sn > 2u) { RN(A0.z); RN(A0.w); }
    if (Sn > 4u) { RN(A1.x); RN(A1.y); }
    if (Sn > 6u) { RN(A1.z); RN(A1.w); }
    if (Sn > 8u) { RN(A2.x); RN(A2.y); }
    if (Sp > 0u) { RP(A2.z); RP(A2.w); }
    if (Sp > 2u) { RP(A3.x); RP(A3.y); }
    if (Sp > 4u) { RP(A3.z); RP(A3.w); }
    if (Sp > 6u) { RP(A4.x); RP(A4.y); }
    if (Sp > 8u) { RP(A4.z); RP(A4.w); }
#undef RN
#undef RP
    prevraw = *(const h2*)(Pb + (ho + pr4));
    h2 bp = hmax2(aN, one2 - aP);
    bp = hmax2(bp, u2h((unsigned)__shfl_xor((int)h2u(bp), 8, 64)));
    bp = hmax2(bp, u2h((unsigned)__shfl_xor((int)h2u(bp), 16, 64)));
    bp = hmax2(bp, u2h((unsigned)__shfl_xor((int)h2u(bp), 32, 64)));
    braw = bp;
  };

  const uint4* Eb = (const uint4*)ents;   // 5 uint4 per (c,g)
  unsigned m0v = meta[0], m1v = meta[1], m2v = meta[2], m3v = meta[3];

  unsigned b0 = (unsigned)g*5u;
  uint4 C0=Eb[b0], C1=Eb[b0+1], C2=Eb[b0+2], C3=Eb[b0+3], C4=Eb[b0+4];
  h2 braw, prevraw;
  runB(m0v, C0,C1,C2,C3,C4, braw, prevraw);

  unsigned b1 = (8u + (unsigned)g)*5u;
  uint4 N0=Eb[b1], N1=Eb[b1+1], N2=Eb[b1+2], N3=Eb[b1+3], N4=Eb[b1+4];
  h2 updprev = zero2;

  #pragma unroll 1
  for (int i = 0; i < CONS; ++i) {
    // B: constraint i+1 (reads precede A's write; hazard slots pre-dummied)
    h2 brawN, prevrawN;
    runB(m1v, N0,N1,N2,N3,N4, brawN, prevrawN);

    // prefetch entries(i+2), meta[i+4]
    unsigned bn = ((unsigned)(i+2)*8u + (unsigned)g)*5u;
    uint4 P0=Eb[bn], P1=Eb[bn+1], P2=Eb[bn+2], P3=Eb[bn+3], P4=Eb[bn+4];
    unsigned m4v = meta[i+4];

    // A: finalize constraint i
    unsigned sc0 = (unsigned)__builtin_amdgcn_readfirstlane((int)m0v);
    h2 body = braw;
    if (sc0 & (1u<<16)) body = hmax2(body, updprev);          // hazard was neg literal: val = p
    if (sc0 & (1u<<17)) body = hmax2(body, one2 - updprev);   // hazard was pos literal: val = 1-p
    h2 prev = (sc0 & (1u<<18)) ? updprev : prevraw;
    h2 upd = (sc0 & (1u<<15)) ? hmax2(prev, one2 - body) : hmin2(prev, body);
    if (lane < 8) *(h2*)(Pb + ((sc0 & 0x7FFFu) + pr4)) = upd;

    updprev = upd;
    braw = brawN; prevraw = prevrawN;
    N0=P0; N1=P1; N2=P2; N3=P3; N4=P4;
    m0v=m1v; m1v=m2v; m2v=m3v; m3v=m4v;
  }

  __syncthreads();
  for (int rr = 0; rr < RPW; ++rr) {
    float* dst = out + (row0+rr)*NUM;
    #pragma unroll
    for (int k = 0; k < NUM/64; ++k) {
      int a = k*64 + lane;
      dst[a] = (float)*(const _Float16*)(Pb + a*ASTR + rr*2);
    }
  }
}

extern "C" void kernel_launch(void* const* d_in, const int* in_sizes, int n_in,
                              void* d_out, int out_size, void* d_ws, size_t ws_size,
                              hipStream_t stream) {
  (void)in_sizes; (void)n_in; (void)out_size; (void)ws_size;
  const float* preds     = (const float*)d_in[0];
  const float* pos       = (const float*)d_in[1];
  const float* neg       = (const float*)d_in[2];
  const int*   head_atom = (const int*)d_in[3];
  const int*   head_sign = (const int*)d_in[4];

  unsigned* meta = (unsigned*)d_ws;                       // 516 words
  unsigned* ents = (unsigned*)((char*)d_ws + 4096);       // 514*8*20*4 ≈ 329 KB

  prep_kernel<<<NMETA, 64, 0, stream>>>(pos, neg, head_atom, head_sign, meta, ents);
  solve_kernel<<<BATCH / RPW, 64, 0, stream>>>(preds, meta, ents, (float*)d_out);
}

// Round 5
// 336.282 us; speedup vs baseline: 4.3489x; 1.2217x over previous
//
#include <hip/hip_runtime.h>

#define BATCH 16384
#define NUM   512
#define CONS  512
#define RPW   16                    // rows per wave/block
#define ASTR  32                    // LDS bytes per atom (16 rows * 2B, power of 2)
#define ZOFF  (NUM*ASTR)            // 128 B zeros scratch (neg dummies, 4 residues)
#define OOFF  (NUM*ASTR + 128)      // 128 B ones scratch (pos dummies)
#define LDSB  (NUM*ASTR + 256)      // 16640
#define NPAD  (CONS + 4)            // pipeline reads/prefetch run 4 constraints past the end
#define EPC   24                    // entry words per (c,g): 10 neg, 10 pos, ho, flags, 2 pad

typedef _Float16 h2 __attribute__((ext_vector_type(2)));
static __device__ __forceinline__ h2 u2h(unsigned u){return __builtin_bit_cast(h2,u);}
static __device__ __forceinline__ unsigned h2u(h2 h){return __builtin_bit_cast(unsigned,h);}
static __device__ __forceinline__ h2 hmax2(h2 a,h2 b){return __builtin_elementwise_max(a,b);}
static __device__ __forceinline__ h2 hmin2(h2 a,h2 b){return __builtin_elementwise_min(a,b);}

// flags word bits: 0 sign | 1 N1 | 2 P1 | 3 N2 | 4 P2 | 5 PR1 | 6 PR2
// N1/P1: a literal (neg/pos) of c equals head(c-1) -> dummied, patch with upd(c-1)
// N2/P2: equals head(c-2) (and not head(c-1))      -> patch with upd(c-2)
// PR1/PR2: head(c) equals head(c-1)/head(c-2)      -> prev comes from upd register
__global__ __launch_bounds__(64) void prep_kernel(
    const float* __restrict__ pos, const float* __restrict__ neg,
    const int* __restrict__ head_atom, const int* __restrict__ head_sign,
    unsigned* __restrict__ ents) {
  int c = blockIdx.x, lane = threadIdx.x;
  unsigned* E = ents + (size_t)c * (8 * EPC);
  if (c >= CONS) {                       // pad constraints: all-dummy, no head effect
    for (int t = lane; t < 8 * EPC; t += 64) {
      int g = t / EPC, k = t % EPC;
      unsigned v = 0;
      if (k < 10) v = ZOFF + (unsigned)(g & 3) * 32u;
      else if (k < 20) v = OOFF + (unsigned)(g & 3) * 32u;
      else if (k == 20) v = ZOFF;        // harmless prev-read target
      E[g * EPC + k] = v;
    }
    return;
  }
  __shared__ int cN[4], cP[4], flg;
  __shared__ unsigned short bN[4][40], bP[4][40];
  __shared__ unsigned sN[80], sP[80], flw;
  if (lane < 4) { cN[lane] = 0; cP[lane] = 0; }
  if (lane == 0) flg = 0;
  __syncthreads();
  int hp1 = (c >= 1) ? head_atom[c - 1] : -1;
  int hp2 = (c >= 2) ? head_atom[c - 2] : -1;
  for (int k = 0; k < NUM / 64; ++k) {
    int a = k * 64 + lane;
    if (neg[(size_t)c * NUM + a] != 0.f) {
      if (a == hp1) atomicOr(&flg, 1 << 1);
      else if (a == hp2) atomicOr(&flg, 1 << 3);
      else { int b = a & 3; int j = atomicAdd(&cN[b], 1); if (j < 40) bN[b][j] = (unsigned short)a; }
    }
    if (pos[(size_t)c * NUM + a] != 0.f) {
      if (a == hp1) atomicOr(&flg, 1 << 2);
      else if (a == hp2) atomicOr(&flg, 1 << 4);
      else { int b = a & 3; int j = atomicAdd(&cP[b], 1); if (j < 40) bP[b][j] = (unsigned short)a; }
    }
  }
  __syncthreads();
  if (lane == 0) {
    int capN[4], capP[4], ptN[4] = {0,0,0,0}, ptP[4] = {0,0,0,0};
    for (int b = 0; b < 4; ++b) { capN[b] = cN[b] < 40 ? cN[b] : 40; capP[b] = cP[b] < 40 ? cP[b] : 40; }
    // deal literals into slots balanced by atom residue (a&3) == slot residue (s&3 == g&3)
    for (int s = 0; s < 80; ++s) {
      int b = s & 3;
      unsigned v = ZOFF + (unsigned)b * 32u;
      for (int t = 0; t < 4; ++t) { int q = b ^ t; if (ptN[q] < capN[q]) { v = (unsigned)bN[q][ptN[q]++] * ASTR; break; } }
      sN[s] = v;
      unsigned w = OOFF + (unsigned)b * 32u;
      for (int t = 0; t < 4; ++t) { int q = b ^ t; if (ptP[q] < capP[q]) { w = (unsigned)bP[q][ptP[q]++] * ASTR; break; } }
      sP[s] = w;
    }
    int hc = head_atom[c];
    unsigned f = (unsigned)flg | (head_sign[c] ? 1u : 0u);
    if (hc == hp1) f |= 1u << 5; else if (hc == hp2) f |= 1u << 6;
    flw = f;
  }
  __syncthreads();
  unsigned hoW = (unsigned)head_atom[c] * ASTR;
  for (int t = lane; t < 8 * EPC; t += 64) {
    int g = t / EPC, k = t % EPC;
    unsigned v;
    if (k < 10) v = sN[k * 8 + g];           // slot s = k*8+g, s&3 == g&3
    else if (k < 20) v = sP[(k - 10) * 8 + g];
    else if (k == 20) v = hoW;
    else if (k == 21) v = flw;
    else v = 0;
    E[g * EPC + k] = v;
  }
}

struct ENT { uint4 e0, e1, e2, e3, e4, e5; };
struct RD  { h2 r[21]; unsigned ho, fl; };
struct ST  { h2 braw, prevraw; unsigned ho, fl; };

static __device__ __forceinline__ ENT ldent(const uint4* T, unsigned c, unsigned g) {
  unsigned b = (c * 8u + g) * 6u;
  ENT e; e.e0 = T[b]; e.e1 = T[b+1]; e.e2 = T[b+2]; e.e3 = T[b+3]; e.e4 = T[b+4]; e.e5 = T[b+5];
  return e;
}
static __device__ __forceinline__ void issue_reads(const ENT& E, const char* Pb, unsigned pr4, RD& R) {
  R.r[0]  = *(const h2*)(Pb + (E.e0.x + pr4));
  R.r[1]  = *(const h2*)(Pb + (E.e0.y + pr4));
  R.r[2]  = *(const h2*)(Pb + (E.e0.z + pr4));
  R.r[3]  = *(const h2*)(Pb + (E.e0.w + pr4));
  R.r[4]  = *(const h2*)(Pb + (E.e1.x + pr4));
  R.r[5]  = *(const h2*)(Pb + (E.e1.y + pr4));
  R.r[6]  = *(const h2*)(Pb + (E.e1.z + pr4));
  R.r[7]  = *(const h2*)(Pb + (E.e1.w + pr4));
  R.r[8]  = *(const h2*)(Pb + (E.e2.x + pr4));
  R.r[9]  = *(const h2*)(Pb + (E.e2.y + pr4));
  R.r[10] = *(const h2*)(Pb + (E.e2.z + pr4));
  R.r[11] = *(const h2*)(Pb + (E.e2.w + pr4));
  R.r[12] = *(const h2*)(Pb + (E.e3.x + pr4));
  R.r[13] = *(const h2*)(Pb + (E.e3.y + pr4));
  R.r[14] = *(const h2*)(Pb + (E.e3.z + pr4));
  R.r[15] = *(const h2*)(Pb + (E.e3.w + pr4));
  R.r[16] = *(const h2*)(Pb + (E.e4.x + pr4));
  R.r[17] = *(const h2*)(Pb + (E.e4.y + pr4));
  R.r[18] = *(const h2*)(Pb + (E.e4.z + pr4));
  R.r[19] = *(const h2*)(Pb + (E.e4.w + pr4));
  R.r[20] = *(const h2*)(Pb + (E.e5.x + pr4));   // prev of head atom
  R.ho = E.e5.x; R.fl = E.e5.y;
}
static __device__ __forceinline__ void combine(const RD& R, ST& S) {
  h2 aN = hmax2(hmax2(hmax2(R.r[0], R.r[1]), hmax2(R.r[2], R.r[3])),
                hmax2(hmax2(R.r[4], R.r[5]), hmax2(R.r[6], R.r[7])));
  aN = hmax2(aN, hmax2(R.r[8], R.r[9]));
  h2 aP = hmin2(hmin2(hmin2(R.r[10], R.r[11]), hmin2(R.r[12], R.r[13])),
                hmin2(hmin2(R.r[14], R.r[15]), hmin2(R.r[16], R.r[17])));
  aP = hmin2(aP, hmin2(R.r[18], R.r[19]));
  const h2 one2 = {(_Float16)1.f, (_Float16)1.f};
  h2 bp = hmax2(aN, one2 - aP);
  bp = hmax2(bp, u2h((unsigned)__shfl_xor((int)h2u(bp), 8, 64)));
  bp = hmax2(bp, u2h((unsigned)__shfl_xor((int)h2u(bp), 16, 64)));
  bp = hmax2(bp, u2h((unsigned)__shfl_xor((int)h2u(bp), 32, 64)));
  S.braw = bp; S.prevraw = R.r[20]; S.ho = R.ho; S.fl = R.fl;
}
static __device__ __forceinline__ h2 finalize(const ST& S, h2 up1, h2 up2,
                                              char* Pb, unsigned pr4, int lane) {
  const h2 one2 = {(_Float16)1.f, (_Float16)1.f};
  unsigned fl = S.fl;
  h2 body = S.braw;                                    // >= 0 by construction
  unsigned mN1 = 0u - ((fl >> 1) & 1u), mP1 = 0u - ((fl >> 2) & 1u);
  unsigned mN2 = 0u - ((fl >> 3) & 1u), mP2 = 0u - ((fl >> 4) & 1u);
  body = hmax2(body, u2h(h2u(up1) & mN1));             // masked-off -> +0 -> identity
  body = hmax2(body, u2h(h2u(one2 - up1) & mP1));
  body = hmax2(body, u2h(h2u(up2) & mN2));
  body = hmax2(body, u2h(h2u(one2 - up2) & mP2));
  unsigned mR1 = 0u - ((fl >> 5) & 1u), mR2 = 0u - ((fl >> 6) & 1u);
  h2 prev = u2h((h2u(up1) & mR1) | (h2u(up2) & mR2) | (h2u(S.prevraw) & ~(mR1 | mR2)));
  unsigned ms = 0u - (fl & 1u);
  h2 uhi = hmax2(prev, one2 - body);
  h2 ulo = hmin2(prev, body);
  h2 upd = u2h((h2u(uhi) & ms) | (h2u(ulo) & ~ms));
  if (lane < 8) *(h2*)(Pb + S.ho + pr4) = upd;
  return upd;
}

__global__ __launch_bounds__(64) void solve_kernel(
    const float* __restrict__ preds,
    const unsigned* __restrict__ ents,
    float* __restrict__ out) {
  __shared__ char Pb[LDSB];
  const int lane = threadIdx.x;
  const int pr = lane & 7, g = lane >> 3;
  const unsigned pr4 = (unsigned)pr * 4u;
  const size_t row0 = (size_t)blockIdx.x * RPW;

  if (lane < 32) *(unsigned*)(Pb + ZOFF + lane * 4) = 0u;
  else           *(unsigned*)(Pb + OOFF + (lane - 32) * 4) = 0x3C003C00u;

  for (int rr = 0; rr < RPW; ++rr) {
    const float* src = preds + (row0 + rr) * NUM;
    #pragma unroll
    for (int k = 0; k < NUM / 64; ++k) {
      int a = k * 64 + lane;
      *(_Float16*)(Pb + a * ASTR + rr * 2) = (_Float16)src[a];
    }
  }
  __syncthreads();

  const uint4* T = (const uint4*)ents;

  // 3-stage pipeline prologue
  ENT E0 = ldent(T, 0u, (unsigned)g);
  ENT E1 = ldent(T, 1u, (unsigned)g);
  ENT Ea = ldent(T, 2u, (unsigned)g);
  ENT Eb = ldent(T, 3u, (unsigned)g);
  RD RA, RB, R0;
  ST S0, S1;
  issue_reads(E0, Pb, pr4, R0);      // reads(0)
  issue_reads(E1, Pb, pr4, RB);      // reads(1), pending into loop
  combine(R0, S0);                   // stage(0)
  h2 up1 = (h2)0.0f, up2 = (h2)0.0f;

  #pragma unroll 1
  for (int i = 0; i < CONS; i += 2) {
    // even body: c = i
    issue_reads(Ea, Pb, pr4, RA);                    // reads(i+2) — hazard-dummied vs heads i, i+1
    { h2 u = finalize(S0, up1, up2, Pb, pr4, lane); up2 = up1; up1 = u; }   // A(i)
    combine(RB, S1);                                 // stage(i+1) from reads(i+1)
    Ea = ldent(T, (unsigned)(i + 4), (unsigned)g);
    // odd body: c = i+1
    issue_reads(Eb, Pb, pr4, RB);                    // reads(i+3)
    { h2 u = finalize(S1, up1, up2, Pb, pr4, lane); up2 = up1; up1 = u; }   // A(i+1)
    combine(RA, S0);                                 // stage(i+2)
    Eb = ldent(T, (unsigned)(i + 5), (unsigned)g);
  }

  __syncthreads();
  for (int rr = 0; rr < RPW; ++rr) {
    float* dst = out + (row0 + rr) * NUM;
    #pragma unroll
    for (int k = 0; k < NUM / 64; ++k) {
      int a = k * 64 + lane;
      dst[a] = (float)*(const _Float16*)(Pb + a * ASTR + rr * 2);
    }
  }
}

extern "C" void kernel_launch(void* const* d_in, const int* in_sizes, int n_in,
                              void* d_out, int out_size, void* d_ws, size_t ws_size,
                              hipStream_t stream) {
  (void)in_sizes; (void)n_in; (void)out_size; (void)ws_size;
  const float* preds     = (const float*)d_in[0];
  const float* pos       = (const float*)d_in[1];
  const float* neg       = (const float*)d_in[2];
  const int*   head_atom = (const int*)d_in[3];
  const int*   head_sign = (const int*)d_in[4];

  unsigned* ents = (unsigned*)d_ws;    // NPAD * 8 * EPC * 4 = 396 KB

  prep_kernel<<<NPAD, 64, 0, stream>>>(pos, neg, head_atom, head_sign, ents);
  solve_kernel<<<BATCH / RPW, 64, 0, stream>>>(preds, ents, (float*)d_out);
}